// Round 16
// baseline (156.673 us; speedup 1.0000x reference)
//
#include <hip/hip_runtime.h>
#include <hip/hip_bf16.h>

#define NNODES 6144
#define FIN    128
#define FOUTC  64
#define NHEAD  2
#define ALPHA  0.2f
#define LN_EPS 1e-5f
#define LOG2E  1.4426950408889634f
#define INVN   (1.0f / 6144.0f)

typedef __attribute__((ext_vector_type(4))) float f32x4;
typedef __attribute__((ext_vector_type(8))) short short8;
typedef __attribute__((ext_vector_type(4))) int   i32x4;

// f32 -> bf16 bits, round-to-nearest-even (k1 packing)
static __device__ __forceinline__ short f2bf(float x) {
    unsigned u = __float_as_uint(x);
    u = (u + 0x7fffu + ((u >> 16) & 1u)) >> 16;
    return (short)u;
}

// HW RNE f32 -> bf16 bits (compiler fuses pairs to v_cvt_pk_bf16_f32)
static __device__ __forceinline__ short f2bf_hw(float x) {
    return (short)__bfloat16_as_ushort(__float2bfloat16(x));
}

// s1,s2 are PRE-SCALED by log2e: unnormalized t = 2^lrelu(e')
static __device__ __forceinline__ float ecalc2(float e, unsigned bit) {
    float m = fmaxf(e, ALPHA * e);
    return bit ? __builtin_amdgcn_exp2f(m) : 0.0f;
}
// normalized p = 2^(lrelu(e') + li), li = -log2(psum); INVN for uni rows
static __device__ __forceinline__ float pcalc2(float e, float li, unsigned bit,
                                               bool uni) {
    float m = fmaxf(e, ALPHA * e) + li;
    float t = bit ? __builtin_amdgcn_exp2f(m) : 0.0f;
    return uni ? INVN : t;
}

// K1: ht = h @ W per head; htbP = bf16 B-fragments pre-packed in MFMA lane order;
// s1/s2 row scores PRE-SCALED by log2e. (unchanged)
__global__ __launch_bounds__(256) void gat_k1(const float* __restrict__ h,
        const float* __restrict__ W, const float* __restrict__ a,
        short* __restrict__ htbP, float* __restrict__ s1, float* __restrict__ s2) {
    __shared__ float hrow[4][FIN];
    const int wid = threadIdx.x >> 6, lane = threadIdx.x & 63;
    const int n = blockIdx.x * 4 + wid;
    hrow[wid][lane]      = h[(size_t)n * FIN + lane];
    hrow[wid][lane + 64] = h[(size_t)n * FIN + lane + 64];
    __syncthreads();
    float acc0 = 0.f, acc1 = 0.f;
    #pragma unroll 8
    for (int k = 0; k < FIN; ++k) {
        float hv = hrow[wid][k];
        acc0 = fmaf(hv, W[k * FOUTC + lane], acc0);
        acc1 = fmaf(hv, W[(FIN + k) * FOUTC + lane], acc1);
    }
    const int it_ = n >> 5, kk = n & 31;
    const int fl  = (lane & 15) + ((kk >> 3) << 4);
    const size_t pb = ((size_t)(it_ * 4 + (lane >> 4))) * 512 + fl * 8 + (kk & 7);
    htbP[pb]          = f2bf(acc0);
    htbP[393216 + pb] = f2bf(acc1);
    float r00 = acc0 * a[lane];
    float r01 = acc0 * a[FOUTC + lane];
    float r10 = acc1 * a[2 * FOUTC + lane];
    float r11 = acc1 * a[3 * FOUTC + lane];
    #pragma unroll
    for (int off = 32; off; off >>= 1) {
        r00 += __shfl_xor(r00, off);
        r01 += __shfl_xor(r01, off);
        r10 += __shfl_xor(r10, off);
        r11 += __shfl_xor(r11, off);
    }
    if (lane == 0) {
        s1[n] = r00 * LOG2E;          s2[n] = r01 * LOG2E;
        s1[NNODES + n] = r10 * LOG2E; s2[NNODES + n] = r11 * LOG2E;
    }
}

// K2a: psum + THREAD-MAJOR mask (maskW2[row][t]: bits 4i..4i+3 = adjacency of
// cols 4t+1024i). Each thread accumulates its own word in-register — no shfl
// packing — and stores it with one coalesced u32 store.
__global__ __launch_bounds__(256) void gat_k2a(const int* __restrict__ adj,
        const float* __restrict__ s1, const float* __restrict__ s2,
        float* __restrict__ psum, unsigned* __restrict__ maskW2) {
    const int n = blockIdx.x;
    const int t = threadIdx.x;
    const int wid = t >> 6, lane = t & 63;
    const i32x4* arow = (const i32x4*)(adj + (size_t)n * NNODES);
    const float4* s2h0 = (const float4*)(s2);
    const float4* s2h1 = (const float4*)(s2 + NNODES);
    const float s10 = s1[n], s11 = s1[NNODES + n];
    float sum0 = 0.f, sum1 = 0.f;
    unsigned myword = 0;
    #pragma unroll
    for (int i = 0; i < 6; ++i) {
        int c4 = t + i * 256;               // cols 4t + 1024i .. +3
        i32x4 av = __builtin_nontemporal_load(arow + c4);
        float4 sa = s2h0[c4];
        float4 sb = s2h1[c4];
        unsigned nib = (unsigned)(av[0] > 0) | ((unsigned)(av[1] > 0) << 1)
                     | ((unsigned)(av[2] > 0) << 2) | ((unsigned)(av[3] > 0) << 3);
        sum0 += (ecalc2(s10 + sa.x, nib & 1u) + ecalc2(s10 + sa.y, nib & 2u))
              + (ecalc2(s10 + sa.z, nib & 4u) + ecalc2(s10 + sa.w, nib & 8u));
        sum1 += (ecalc2(s11 + sb.x, nib & 1u) + ecalc2(s11 + sb.y, nib & 2u))
              + (ecalc2(s11 + sb.z, nib & 4u) + ecalc2(s11 + sb.w, nib & 8u));
        myword |= nib << (4 * i);
    }
    maskW2[(size_t)n * 256 + t] = myword;
    #pragma unroll
    for (int off = 32; off; off >>= 1) {
        sum0 += __shfl_xor(sum0, off);
        sum1 += __shfl_xor(sum1, off);
    }
    __shared__ float red[2][4];
    if (lane == 0) { red[0][wid] = sum0; red[1][wid] = sum1; }
    __syncthreads();
    if (t == 0) {
        psum[n]          = (red[0][0] + red[0][1]) + (red[0][2] + red[0][3]);
        psum[NNODES + n] = (red[1][0] + red[1][1]) + (red[1][2] + red[1][3]);
    }
}

// MIXED grid: every RATIO-th block = M (MFMA); others = W (att writer, 4 rows x
// 1 head — one s2 load feeds 4 stores; mask preloaded 1 word/row/thread).
template <int ITERS, int RATIO>
__global__ __launch_bounds__(256) void gat_mixed(const unsigned* __restrict__ maskW2,
        const short* __restrict__ htbP, const float* __restrict__ s1,
        const float* __restrict__ s2, const float* __restrict__ psum,
        float* __restrict__ att, float* __restrict__ hpp) {
    const int bid = blockIdx.x;
    const int mid = bid / RATIO, rem = bid % RATIO;

    if (rem == RATIO - 1) {
        // ---------------- M block: MFMA, exponent-folded normalize ----------------
        const int bx = (6144 / ITERS / 32 == 4) ? (mid & 1) : 0;
        const int by = (6144 / ITERS / 32 == 4) ? (mid >> 1) : mid;
        const int w = threadIdx.x >> 6, lane = threadIdx.x & 63;
        const int hh = w & 1, cs = w >> 1;
        const int pc = bx * 2 + cs;
        const int n0 = by * 16;
        const int r = lane & 15, g = lane >> 4;
        const int node = n0 + r;
        const float s1v = s1[hh * NNODES + node];
        const float ps  = psum[hh * NNODES + node];
        const bool uni = !(ps > 0.f);
        const float li = uni ? 0.f : -__log2f(ps);
        const float* s2h = s2 + hh * NNODES;
        const unsigned* mrowW = maskW2 + (size_t)node * 256;
        const short* bb = htbP + (size_t)(hh * 192 + pc * ITERS) * 2048 + (size_t)lane * 8;
        const int cbase = pc * ITERS * 32;

        f32x4 acc0 = {0.f,0.f,0.f,0.f}, acc1 = {0.f,0.f,0.f,0.f};
        f32x4 acc2 = {0.f,0.f,0.f,0.f}, acc3 = {0.f,0.f,0.f,0.f};

        #pragma unroll 4
        for (int it = 0; it < ITERS; ++it) {
            const int kb = cbase + it * 32 + g * 8;
            const int t0 = (kb & 1023) >> 2, inib = (kb >> 10) * 4;
            const unsigned w0 = mrowW[t0], w1 = mrowW[t0 + 1];
            const unsigned mb = ((w0 >> inib) & 0xfu) | (((w1 >> inib) & 0xfu) << 4);
            float4 sa = *(const float4*)(s2h + kb);
            float4 sb = *(const float4*)(s2h + kb + 4);
            float p0 = pcalc2(s1v + sa.x, li, mb & 1u,   uni);
            float p1 = pcalc2(s1v + sa.y, li, mb & 2u,   uni);
            float p2 = pcalc2(s1v + sa.z, li, mb & 4u,   uni);
            float p3 = pcalc2(s1v + sa.w, li, mb & 8u,   uni);
            float p4 = pcalc2(s1v + sb.x, li, mb & 16u,  uni);
            float p5 = pcalc2(s1v + sb.y, li, mb & 32u,  uni);
            float p6 = pcalc2(s1v + sb.z, li, mb & 64u,  uni);
            float p7 = pcalc2(s1v + sb.w, li, mb & 128u, uni);
            short8 af = { f2bf_hw(p0), f2bf_hw(p1), f2bf_hw(p2), f2bf_hw(p3),
                          f2bf_hw(p4), f2bf_hw(p5), f2bf_hw(p6), f2bf_hw(p7) };
            const short* bp = bb + (size_t)it * 2048;
            short8 b0 = *(const short8*)(bp);
            short8 b1 = *(const short8*)(bp + 512);
            short8 b2 = *(const short8*)(bp + 1024);
            short8 b3 = *(const short8*)(bp + 1536);
            acc0 = __builtin_amdgcn_mfma_f32_16x16x32_bf16(af, b0, acc0, 0, 0, 0);
            acc1 = __builtin_amdgcn_mfma_f32_16x16x32_bf16(af, b1, acc1, 0, 0, 0);
            acc2 = __builtin_amdgcn_mfma_f32_16x16x32_bf16(af, b2, acc2, 0, 0, 0);
            acc3 = __builtin_amdgcn_mfma_f32_16x16x32_bf16(af, b3, acc3, 0, 0, 0);
        }
        float* hb = hpp + ((size_t)(pc * NHEAD + hh) * NNODES + (n0 + g * 4)) * FOUTC + r;
        #pragma unroll
        for (int reg = 0; reg < 4; ++reg) {
            hb[(size_t)reg * FOUTC +  0] = acc0[reg];
            hb[(size_t)reg * FOUTC + 16] = acc1[reg];
            hb[(size_t)reg * FOUTC + 32] = acc2[reg];
            hb[(size_t)reg * FOUTC + 48] = acc3[reg];
        }
    } else {
        // ------------- W block: 4 rows x 1 head (s2 load amortized 4x) -------------
        const int idx = mid * (RATIO - 1) + rem;     // 0 .. 3071
        const int hh  = idx / 1536;
        const int row0 = (idx - hh * 1536) * 4;
        const int t = threadIdx.x;
        const float* s2h = s2 + hh * NNODES;
        float s1v[4], li[4];
        bool uni[4];
        unsigned mw[4];
        #pragma unroll
        for (int r = 0; r < 4; ++r) {
            const float ps = psum[hh * NNODES + row0 + r];
            uni[r] = !(ps > 0.f);
            li[r]  = uni[r] ? 0.f : -__log2f(ps);
            s1v[r] = s1[hh * NNODES + row0 + r];
            mw[r]  = maskW2[(size_t)(row0 + r) * 256 + t];
        }
        float* attr = att + ((size_t)hh * NNODES + row0) * NNODES;
        #pragma unroll
        for (int i = 0; i < 6; ++i) {
            const int c0 = i * 1024 + t * 4;
            float4 sv = *(const float4*)(s2h + c0);   // one load, 4 stores
            #pragma unroll
            for (int r = 0; r < 4; ++r) {
                const unsigned bits = (mw[r] >> (4 * i)) & 0xfu;
                f32x4 st = { pcalc2(s1v[r] + sv.x, li[r], bits & 1u, uni[r]),
                             pcalc2(s1v[r] + sv.y, li[r], bits & 2u, uni[r]),
                             pcalc2(s1v[r] + sv.z, li[r], bits & 4u, uni[r]),
                             pcalc2(s1v[r] + sv.w, li[r], bits & 8u, uni[r]) };
                __builtin_nontemporal_store(st,
                    (f32x4*)(attr + (size_t)r * NNODES + c0));
            }
        }
    }
}

// K4: sum nchunk hp partials per head, layernorm over 128 features, write out
__global__ __launch_bounds__(256) void gat_k4(const float* __restrict__ hpp,
        const float* __restrict__ gamma, const float* __restrict__ beta,
        float* __restrict__ out, int nchunk) {
    const int wid = threadIdx.x >> 6, lane = threadIdx.x & 63;
    const int n = blockIdx.x * 4 + wid;
    float v0 = 0.f, v1 = 0.f;
    for (int p = 0; p < nchunk; ++p) {
        v0 += hpp[((size_t)(p * NHEAD + 0) * NNODES + n) * FOUTC + lane];
        v1 += hpp[((size_t)(p * NHEAD + 1) * NNODES + n) * FOUTC + lane];
    }
    float s = v0 + v1;
    #pragma unroll
    for (int off = 32; off; off >>= 1) s += __shfl_xor(s, off);
    const float mu = s * (1.0f / 128.0f);
    const float d0 = v0 - mu, d1 = v1 - mu;
    float q = d0 * d0 + d1 * d1;
    #pragma unroll
    for (int off = 32; off; off >>= 1) q += __shfl_xor(q, off);
    const float rstd = 1.0f / sqrtf(q * (1.0f / 128.0f) + LN_EPS);
    out[(size_t)n * 128 + lane]      = d0 * rstd * gamma[lane] + beta[lane];
    out[(size_t)n * 128 + 64 + lane] = d1 * rstd * gamma[64 + lane] + beta[64 + lane];
}

extern "C" void kernel_launch(void* const* d_in, const int* in_sizes, int n_in,
                              void* d_out, int out_size, void* d_ws, size_t ws_size,
                              hipStream_t stream) {
    const float* h     = (const float*)d_in[0];
    const int*   adj   = (const int*)d_in[1];
    const float* W     = (const float*)d_in[2];
    const float* a     = (const float*)d_in[3];
    const float* gamma = (const float*)d_in[4];
    const float* beta  = (const float*)d_in[5];
    float* out = (float*)d_out;
    float* att = out + (size_t)NNODES * (NHEAD * FOUTC);   // out first, then att

    char* ws = (char*)d_ws;
    short* htbP = (short*)ws;                                // 1,572,864 B
    float* s1   = (float*)(ws + 1572864);                    // 49,152 B
    float* s2p  = (float*)(ws + 1572864 + 49152);            // 49,152 B
    float* psum = (float*)(ws + 1572864 + 2 * 49152);        // 49,152 B
    unsigned* maskW2 = (unsigned*)(ws + 1572864 + 3 * 49152);// 6,291,456 B
    char* hpp_base = ws + 1572864 + 3 * 49152 + 6291456;     // = 8,011,776
    size_t avail = (ws_size > 8011776) ? ws_size - 8011776 : 0;
    const size_t per_chunk = (size_t)NHEAD * NNODES * FOUTC * 4;     // 3,145,728 B
    const int nchunk = (avail >= 4 * per_chunk) ? 4 : 2;
    float* hpp = (float*)hpp_base;

    gat_k1<<<NNODES / 4, 256, 0, stream>>>(h, W, a, htbP, s1, s2p);
    gat_k2a<<<NNODES, 256, 0, stream>>>(adj, s1, s2p, psum, maskW2);
    if (nchunk == 4) {
        // 3072 W (4-row) + 768 M = 3840 blocks, 1 M per 5
        gat_mixed<48, 5><<<3840, 256, 0, stream>>>(maskW2, htbP, s1, s2p, psum, att, hpp);
    } else {
        // 3072 W + 384 M = 3456 blocks, 1 M per 9
        gat_mixed<96, 9><<<3456, 256, 0, stream>>>(maskW2, htbP, s1, s2p, psum, att, hpp);
    }
    gat_k4<<<NNODES / 4, 256, 0, stream>>>(hpp, gamma, beta, out, nchunk);
}

// Round 17
// 146.249 us; speedup vs baseline: 1.0713x; 1.0713x over previous
//
#include <hip/hip_runtime.h>
#include <hip/hip_bf16.h>

#define NNODES 6144
#define FIN    128
#define FOUTC  64
#define NHEAD  2
#define ALPHA  0.2f
#define LN_EPS 1e-5f
#define MASKW  192                      // u32 words per row (6144/32)

typedef __attribute__((ext_vector_type(4))) float f32x4;
typedef __attribute__((ext_vector_type(8))) short short8;
typedef __attribute__((ext_vector_type(4))) int   i32x4;

// f32 -> bf16 bits, round-to-nearest-even (k1 packing)
static __device__ __forceinline__ short f2bf(float x) {
    unsigned u = __float_as_uint(x);
    u = (u + 0x7fffu + ((u >> 16) & 1u)) >> 16;
    return (short)u;
}

// HW RNE f32 -> bf16 bits (compiler fuses pairs to v_cvt_pk_bf16_f32)
static __device__ __forceinline__ short f2bf_hw(float x) {
    return (short)__bfloat16_as_ushort(__float2bfloat16(x));
}

// p = (uni ? 1 : (bit ? exp(lrelu(s1+s2)) : 0)) * inv
static __device__ __forceinline__ float pcalc(float s1v, float s2v, unsigned bit,
                                              bool uni, float inv) {
    float e = s1v + s2v;
    e = fmaxf(e, ALPHA * e);
    float t = bit ? __expf(e) : 0.0f;
    t = uni ? 1.0f : t;
    return t * inv;
}

// unnormalized exp term (int adjacency)
static __device__ __forceinline__ float ecalc(float s1v, float s2v, int am) {
    float e = s1v + s2v;
    e = fmaxf(e, ALPHA * e);
    return (am > 0) ? __expf(e) : 0.0f;
}

// unnormalized term: uni ? 1 : (bit ? exp(lrelu) : 0)
static __device__ __forceinline__ float tcalc(float s1v, float s2v, unsigned bit,
                                              bool uni) {
    float e = s1v + s2v;
    e = fmaxf(e, ALPHA * e);
    float t = bit ? __expf(e) : 0.0f;
    return uni ? 1.0f : t;
}

// K1: unchanged, proven.
__global__ __launch_bounds__(256) void gat_k1(const float* __restrict__ h,
        const float* __restrict__ W, const float* __restrict__ a,
        short* __restrict__ htbP, float* __restrict__ s1, float* __restrict__ s2) {
    __shared__ float hrow[4][FIN];
    const int wid = threadIdx.x >> 6, lane = threadIdx.x & 63;
    const int n = blockIdx.x * 4 + wid;
    hrow[wid][lane]      = h[(size_t)n * FIN + lane];
    hrow[wid][lane + 64] = h[(size_t)n * FIN + lane + 64];
    __syncthreads();
    float acc0 = 0.f, acc1 = 0.f;
    #pragma unroll 8
    for (int k = 0; k < FIN; ++k) {
        float hv = hrow[wid][k];
        acc0 = fmaf(hv, W[k * FOUTC + lane], acc0);
        acc1 = fmaf(hv, W[(FIN + k) * FOUTC + lane], acc1);
    }
    const int it_ = n >> 5, kk = n & 31;
    const int fl  = (lane & 15) + ((kk >> 3) << 4);
    const size_t pb = ((size_t)(it_ * 4 + (lane >> 4))) * 512 + fl * 8 + (kk & 7);
    htbP[pb]          = f2bf(acc0);
    htbP[393216 + pb] = f2bf(acc1);
    float r00 = acc0 * a[lane];
    float r01 = acc0 * a[FOUTC + lane];
    float r10 = acc1 * a[2 * FOUTC + lane];
    float r11 = acc1 * a[3 * FOUTC + lane];
    #pragma unroll
    for (int off = 32; off; off >>= 1) {
        r00 += __shfl_xor(r00, off);
        r01 += __shfl_xor(r01, off);
        r10 += __shfl_xor(r10, off);
        r11 += __shfl_xor(r11, off);
    }
    if (lane == 0) {
        s1[n] = r00;          s2[n] = r01;
        s1[NNODES + n] = r10; s2[NNODES + n] = r11;
    }
}

// K2a: psum + bitmask only (R13 verbatim). Streams adj once (nt).
__global__ __launch_bounds__(256) void gat_k2a(const int* __restrict__ adj,
        const float* __restrict__ s1, const float* __restrict__ s2,
        float* __restrict__ psum, unsigned* __restrict__ mask32) {
    const int n = blockIdx.x;
    const int t = threadIdx.x;
    const int wid = t >> 6, lane = t & 63;
    const i32x4* arow = (const i32x4*)(adj + (size_t)n * NNODES);
    const float4* s2h0 = (const float4*)(s2);
    const float4* s2h1 = (const float4*)(s2 + NNODES);
    const float s10 = s1[n], s11 = s1[NNODES + n];
    float sum0 = 0.f, sum1 = 0.f;
    unsigned* mrow = mask32 + (size_t)n * MASKW;
    #pragma unroll
    for (int i = 0; i < 6; ++i) {
        int c4 = t + i * 256;
        i32x4 av = __builtin_nontemporal_load(arow + c4);
        float4 sa = s2h0[c4];
        float4 sb = s2h1[c4];
        sum0 += (ecalc(s10, sa.x, av[0]) + ecalc(s10, sa.y, av[1]))
              + (ecalc(s10, sa.z, av[2]) + ecalc(s10, sa.w, av[3]));
        sum1 += (ecalc(s11, sb.x, av[0]) + ecalc(s11, sb.y, av[1]))
              + (ecalc(s11, sb.z, av[2]) + ecalc(s11, sb.w, av[3]));
        unsigned nib = (unsigned)(av[0] > 0) | ((unsigned)(av[1] > 0) << 1)
                     | ((unsigned)(av[2] > 0) << 2) | ((unsigned)(av[3] > 0) << 3);
        unsigned v = nib << ((lane & 7) * 4);
        v |= (unsigned)__shfl_xor((int)v, 1);
        v |= (unsigned)__shfl_xor((int)v, 2);
        v |= (unsigned)__shfl_xor((int)v, 4);
        if ((lane & 7) == 0)
            mrow[i * 32 + wid * 8 + (lane >> 3)] = v;
    }
    #pragma unroll
    for (int off = 32; off; off >>= 1) {
        sum0 += __shfl_xor(sum0, off);
        sum1 += __shfl_xor(sum1, off);
    }
    __shared__ float red[2][4];
    if (lane == 0) { red[0][wid] = sum0; red[1][wid] = sum1; }
    __syncthreads();
    if (t == 0) {
        psum[n]          = (red[0][0] + red[0][1]) + (red[0][2] + red[0][3]);
        psum[NNODES + n] = (red[1][0] + red[1][1]) + (red[1][2] + red[1][3]);
    }
}

// MIXED grid, FRONT-LOADED M: blocks 0..2*NM-1 alternate M/W (even=M), so all
// M blocks are resident from T~0 and overlap the W store stream; blocks >= 2*NM
// are all W. Bodies are R13-verbatim.
template <int ITERS>
__global__ __launch_bounds__(256) void gat_mixed(const unsigned* __restrict__ mask32,
        const short* __restrict__ htbP, const float* __restrict__ s1,
        const float* __restrict__ s2, const float* __restrict__ psum,
        float* __restrict__ att, float* __restrict__ hpp) {
    constexpr int NCH = 6144 / (ITERS * 32);     // col chunks (8/4/2)
    constexpr int NM  = NCH * 192;               // M block count
    const int bid = blockIdx.x;
    bool isM;
    int mid;
    if (bid < 2 * NM) { isM = !(bid & 1); mid = bid >> 1; }
    else              { isM = false;      mid = bid - NM; }

    if (isM) {
        // ---------------- M block (champion k3a, R13 verbatim) ----------------
        constexpr int BXN = (NCH / 2 > 0) ? NCH / 2 : 1;
        const int bx = mid % BXN;
        const int by = mid / BXN;
        const int w = threadIdx.x >> 6, lane = threadIdx.x & 63;
        const int hh = w & 1, cs = w >> 1;
        const int pc = bx * 2 + cs;
        const int n0 = by * 16;
        const int r = lane & 15, g = lane >> 4;
        const int node = n0 + r;
        const float s1v = s1[hh * NNODES + node];
        const float ps  = psum[hh * NNODES + node];
        const bool uni = !(ps > 0.f);
        const float* s2h = s2 + hh * NNODES;
        const unsigned* mrow = mask32 + (size_t)node * MASKW + pc * ITERS;
        const short* bb = htbP + (size_t)(hh * 192 + pc * ITERS) * 2048 + (size_t)lane * 8;
        const int cbase = pc * ITERS * 32;

        f32x4 acc0 = {0.f,0.f,0.f,0.f}, acc1 = {0.f,0.f,0.f,0.f};
        f32x4 acc2 = {0.f,0.f,0.f,0.f}, acc3 = {0.f,0.f,0.f,0.f};

        #pragma unroll 4
        for (int it = 0; it < ITERS; ++it) {
            const int kb = cbase + it * 32 + g * 8;
            const unsigned mb = (mrow[it] >> (g * 8)) & 0xffu;
            float4 sa = *(const float4*)(s2h + kb);
            float4 sb = *(const float4*)(s2h + kb + 4);
            float t0 = tcalc(s1v, sa.x, mb & 1u,   uni);
            float t1 = tcalc(s1v, sa.y, mb & 2u,   uni);
            float t2 = tcalc(s1v, sa.z, mb & 4u,   uni);
            float t3 = tcalc(s1v, sa.w, mb & 8u,   uni);
            float t4 = tcalc(s1v, sb.x, mb & 16u,  uni);
            float t5 = tcalc(s1v, sb.y, mb & 32u,  uni);
            float t6 = tcalc(s1v, sb.z, mb & 64u,  uni);
            float t7 = tcalc(s1v, sb.w, mb & 128u, uni);
            short8 af = { f2bf_hw(t0), f2bf_hw(t1), f2bf_hw(t2), f2bf_hw(t3),
                          f2bf_hw(t4), f2bf_hw(t5), f2bf_hw(t6), f2bf_hw(t7) };
            const short* bp = bb + (size_t)it * 2048;
            short8 b0 = *(const short8*)(bp);
            short8 b1 = *(const short8*)(bp + 512);
            short8 b2 = *(const short8*)(bp + 1024);
            short8 b3 = *(const short8*)(bp + 1536);
            acc0 = __builtin_amdgcn_mfma_f32_16x16x32_bf16(af, b0, acc0, 0, 0, 0);
            acc1 = __builtin_amdgcn_mfma_f32_16x16x32_bf16(af, b1, acc1, 0, 0, 0);
            acc2 = __builtin_amdgcn_mfma_f32_16x16x32_bf16(af, b2, acc2, 0, 0, 0);
            acc3 = __builtin_amdgcn_mfma_f32_16x16x32_bf16(af, b3, acc3, 0, 0, 0);
        }
        // post-normalize with OUTPUT row's denominator (R8 bug class guarded)
        float invO[4];
        #pragma unroll
        for (int reg = 0; reg < 4; ++reg) {
            float pso = psum[hh * NNODES + n0 + g * 4 + reg];
            invO[reg] = (pso > 0.f) ? (1.0f / pso) : (1.0f / (float)NNODES);
        }
        float* hb = hpp + ((size_t)(pc * NHEAD + hh) * NNODES + (n0 + g * 4)) * FOUTC + r;
        #pragma unroll
        for (int reg = 0; reg < 4; ++reg) {
            hb[(size_t)reg * FOUTC +  0] = acc0[reg] * invO[reg];
            hb[(size_t)reg * FOUTC + 16] = acc1[reg] * invO[reg];
            hb[(size_t)reg * FOUTC + 32] = acc2[reg] * invO[reg];
            hb[(size_t)reg * FOUTC + 48] = acc3[reg] * invO[reg];
        }
    } else {
        // ---------------- W block (att writer, R13 verbatim) ----------------
        const int row = mid;
        const int t = threadIdx.x;
        const float ps0 = psum[row],          ps1 = psum[NNODES + row];
        const bool u0 = !(ps0 > 0.f),         u1 = !(ps1 > 0.f);
        const float in0 = u0 ? (1.0f / (float)NNODES) : 1.0f / ps0;
        const float in1 = u1 ? (1.0f / (float)NNODES) : 1.0f / ps1;
        const float s10 = s1[row], s11 = s1[NNODES + row];
        const unsigned* mrow = mask32 + (size_t)row * MASKW;
        float* attr0 = att + (size_t)row * NNODES;
        float* attr1 = attr0 + (size_t)NNODES * NNODES;
        const int sh = (t & 7) * 4;
        #pragma unroll
        for (int i = 0; i < 6; ++i) {
            const int c0 = i * 1024 + t * 4;
            const unsigned bits = (mrow[c0 >> 5] >> sh) & 0xfu;
            float4 sv0 = *(const float4*)(s2 + c0);
            float4 sv1 = *(const float4*)(s2 + NNODES + c0);
            f32x4 st0 = { pcalc(s10, sv0.x, bits & 1u, u0, in0),
                          pcalc(s10, sv0.y, bits & 2u, u0, in0),
                          pcalc(s10, sv0.z, bits & 4u, u0, in0),
                          pcalc(s10, sv0.w, bits & 8u, u0, in0) };
            f32x4 st1 = { pcalc(s11, sv1.x, bits & 1u, u1, in1),
                          pcalc(s11, sv1.y, bits & 2u, u1, in1),
                          pcalc(s11, sv1.z, bits & 4u, u1, in1),
                          pcalc(s11, sv1.w, bits & 8u, u1, in1) };
            __builtin_nontemporal_store(st0, (f32x4*)(attr0 + c0));
            __builtin_nontemporal_store(st1, (f32x4*)(attr1 + c0));
        }
    }
}

// K4: sum nchunk hp partials per head, layernorm over 128 features, write out
__global__ __launch_bounds__(256) void gat_k4(const float* __restrict__ hpp,
        const float* __restrict__ gamma, const float* __restrict__ beta,
        float* __restrict__ out, int nchunk) {
    const int wid = threadIdx.x >> 6, lane = threadIdx.x & 63;
    const int n = blockIdx.x * 4 + wid;
    float v0 = 0.f, v1 = 0.f;
    for (int p = 0; p < nchunk; ++p) {
        v0 += hpp[((size_t)(p * NHEAD + 0) * NNODES + n) * FOUTC + lane];
        v1 += hpp[((size_t)(p * NHEAD + 1) * NNODES + n) * FOUTC + lane];
    }
    float s = v0 + v1;
    #pragma unroll
    for (int off = 32; off; off >>= 1) s += __shfl_xor(s, off);
    const float mu = s * (1.0f / 128.0f);
    const float d0 = v0 - mu, d1 = v1 - mu;
    float q = d0 * d0 + d1 * d1;
    #pragma unroll
    for (int off = 32; off; off >>= 1) q += __shfl_xor(q, off);
    const float rstd = 1.0f / sqrtf(q * (1.0f / 128.0f) + LN_EPS);
    out[(size_t)n * 128 + lane]      = d0 * rstd * gamma[lane] + beta[lane];
    out[(size_t)n * 128 + 64 + lane] = d1 * rstd * gamma[64 + lane] + beta[64 + lane];
}

extern "C" void kernel_launch(void* const* d_in, const int* in_sizes, int n_in,
                              void* d_out, int out_size, void* d_ws, size_t ws_size,
                              hipStream_t stream) {
    const float* h     = (const float*)d_in[0];
    const int*   adj   = (const int*)d_in[1];
    const float* W     = (const float*)d_in[2];
    const float* a     = (const float*)d_in[3];
    const float* gamma = (const float*)d_in[4];
    const float* beta  = (const float*)d_in[5];
    float* out = (float*)d_out;
    float* att = out + (size_t)NNODES * (NHEAD * FOUTC);   // out first, then att

    char* ws = (char*)d_ws;
    short* htbP = (short*)ws;                               // 1,572,864 B
    float* s1   = (float*)(ws + 1572864);                   // 49,152 B
    float* s2p  = (float*)(ws + 1572864 + 49152);           // 49,152 B
    float* psum = (float*)(ws + 1572864 + 2 * 49152);       // 49,152 B
    unsigned* mask32 = (unsigned*)(ws + 1572864 + 3 * 49152);        // 4,718,592 B
    char* hpp_base = ws + 1572864 + 3 * 49152 + 4718592;             // = 6,438,912
    size_t avail = (ws_size > 6438912) ? ws_size - 6438912 : 0;
    const size_t per_chunk = (size_t)NHEAD * NNODES * FOUTC * 4;     // 3,145,728 B
    int nchunk = 2;
    if (avail >= 8 * per_chunk)      nchunk = 8;
    else if (avail >= 4 * per_chunk) nchunk = 4;
    float* hpp = (float*)hpp_base;

    gat_k1<<<NNODES / 4, 256, 0, stream>>>(h, W, a, htbP, s1, s2p);
    gat_k2a<<<NNODES, 256, 0, stream>>>(adj, s1, s2p, psum, mask32);
    if (nchunk == 8) {
        // 1536 M + 6144 W; first 3072 blocks alternate M/W
        gat_mixed<24><<<1536 + 6144, 256, 0, stream>>>(mask32, htbP, s1, s2p, psum, att, hpp);
    } else if (nchunk == 4) {
        // 768 M + 6144 W; first 1536 blocks alternate M/W
        gat_mixed<48><<<768 + 6144, 256, 0, stream>>>(mask32, htbP, s1, s2p, psum, att, hpp);
    } else {
        // 384 M + 6144 W; first 768 blocks alternate M/W
        gat_mixed<96><<<384 + 6144, 256, 0, stream>>>(mask32, htbP, s1, s2p, psum, att, hpp);
    }
    gat_k4<<<NNODES / 4, 256, 0, stream>>>(hpp, gamma, beta, out, nchunk);
}

// Round 18
// 127.055 us; speedup vs baseline: 1.2331x; 1.1511x over previous
//
#include <hip/hip_runtime.h>
#include <hip/hip_bf16.h>

#define NNODES 6144
#define FIN    128
#define FOUTC  64
#define NHEAD  2
#define ALPHA  0.2f
#define LN_EPS 1e-5f
#define MASKW  192                      // u32 words per row (6144/32)

typedef __attribute__((ext_vector_type(4))) float f32x4;
typedef __attribute__((ext_vector_type(8))) short short8;
typedef __attribute__((ext_vector_type(4))) int   i32x4;

// f32 -> bf16 bits, round-to-nearest-even (k1 packing)
static __device__ __forceinline__ short f2bf(float x) {
    unsigned u = __float_as_uint(x);
    u = (u + 0x7fffu + ((u >> 16) & 1u)) >> 16;
    return (short)u;
}

// HW RNE f32 -> bf16 bits (compiler fuses pairs to v_cvt_pk_bf16_f32)
static __device__ __forceinline__ short f2bf_hw(float x) {
    return (short)__bfloat16_as_ushort(__float2bfloat16(x));
}

// p = (uni ? 1 : (bit ? exp(lrelu(s1+s2)) : 0)) * inv   (R5-proven semantics)
static __device__ __forceinline__ float pcalc(float s1v, float s2v, unsigned bit,
                                              bool uni, float inv) {
    float e = s1v + s2v;
    e = fmaxf(e, ALPHA * e);
    float t = bit ? __expf(e) : 0.0f;
    t = uni ? 1.0f : t;
    return t * inv;
}

// unnormalized exp term (int adjacency)
static __device__ __forceinline__ float ecalc(float s1v, float s2v, int am) {
    float e = s1v + s2v;
    e = fmaxf(e, ALPHA * e);
    return (am > 0) ? __expf(e) : 0.0f;
}

// K1: unchanged, proven.
__global__ __launch_bounds__(256) void gat_k1(const float* __restrict__ h,
        const float* __restrict__ W, const float* __restrict__ a,
        short* __restrict__ htbP, float* __restrict__ s1, float* __restrict__ s2) {
    __shared__ float hrow[4][FIN];
    const int wid = threadIdx.x >> 6, lane = threadIdx.x & 63;
    const int n = blockIdx.x * 4 + wid;
    hrow[wid][lane]      = h[(size_t)n * FIN + lane];
    hrow[wid][lane + 64] = h[(size_t)n * FIN + lane + 64];
    __syncthreads();
    float acc0 = 0.f, acc1 = 0.f;
    #pragma unroll 8
    for (int k = 0; k < FIN; ++k) {
        float hv = hrow[wid][k];
        acc0 = fmaf(hv, W[k * FOUTC + lane], acc0);
        acc1 = fmaf(hv, W[(FIN + k) * FOUTC + lane], acc1);
    }
    const int it_ = n >> 5, kk = n & 31;
    const int fl  = (lane & 15) + ((kk >> 3) << 4);
    const size_t pb = ((size_t)(it_ * 4 + (lane >> 4))) * 512 + fl * 8 + (kk & 7);
    htbP[pb]          = f2bf(acc0);
    htbP[393216 + pb] = f2bf(acc1);
    float r00 = acc0 * a[lane];
    float r01 = acc0 * a[FOUTC + lane];
    float r10 = acc1 * a[2 * FOUTC + lane];
    float r11 = acc1 * a[3 * FOUTC + lane];
    #pragma unroll
    for (int off = 32; off; off >>= 1) {
        r00 += __shfl_xor(r00, off);
        r01 += __shfl_xor(r01, off);
        r10 += __shfl_xor(r10, off);
        r11 += __shfl_xor(r11, off);
    }
    if (lane == 0) {
        s1[n] = r00;          s2[n] = r01;
        s1[NNODES + n] = r10; s2[NNODES + n] = r11;
    }
}

// K2a: psum + bitmask only (R13 verbatim). Streams adj once (nt).
__global__ __launch_bounds__(256) void gat_k2a(const int* __restrict__ adj,
        const float* __restrict__ s1, const float* __restrict__ s2,
        float* __restrict__ psum, unsigned* __restrict__ mask32) {
    const int n = blockIdx.x;
    const int t = threadIdx.x;
    const int wid = t >> 6, lane = t & 63;
    const i32x4* arow = (const i32x4*)(adj + (size_t)n * NNODES);
    const float4* s2h0 = (const float4*)(s2);
    const float4* s2h1 = (const float4*)(s2 + NNODES);
    const float s10 = s1[n], s11 = s1[NNODES + n];
    float sum0 = 0.f, sum1 = 0.f;
    unsigned* mrow = mask32 + (size_t)n * MASKW;
    #pragma unroll
    for (int i = 0; i < 6; ++i) {
        int c4 = t + i * 256;
        i32x4 av = __builtin_nontemporal_load(arow + c4);
        float4 sa = s2h0[c4];
        float4 sb = s2h1[c4];
        sum0 += (ecalc(s10, sa.x, av[0]) + ecalc(s10, sa.y, av[1]))
              + (ecalc(s10, sa.z, av[2]) + ecalc(s10, sa.w, av[3]));
        sum1 += (ecalc(s11, sb.x, av[0]) + ecalc(s11, sb.y, av[1]))
              + (ecalc(s11, sb.z, av[2]) + ecalc(s11, sb.w, av[3]));
        unsigned nib = (unsigned)(av[0] > 0) | ((unsigned)(av[1] > 0) << 1)
                     | ((unsigned)(av[2] > 0) << 2) | ((unsigned)(av[3] > 0) << 3);
        unsigned v = nib << ((lane & 7) * 4);
        v |= (unsigned)__shfl_xor((int)v, 1);
        v |= (unsigned)__shfl_xor((int)v, 2);
        v |= (unsigned)__shfl_xor((int)v, 4);
        if ((lane & 7) == 0)
            mrow[i * 32 + wid * 8 + (lane >> 3)] = v;
    }
    #pragma unroll
    for (int off = 32; off; off >>= 1) {
        sum0 += __shfl_xor(sum0, off);
        sum1 += __shfl_xor(sum1, off);
    }
    __shared__ float red[2][4];
    if (lane == 0) { red[0][wid] = sum0; red[1][wid] = sum1; }
    __syncthreads();
    if (t == 0) {
        psum[n]          = (red[0][0] + red[0][1]) + (red[0][2] + red[0][3]);
        psum[NNODES + n] = (red[1][0] + red[1][1]) + (red[1][2] + red[1][3]);
    }
}

// M-ONLY fused kernel: computes p ONCE per element (in-loop normalized, R5
// semantics), feeds MFMA, AND writes att via wave-private LDS transpose:
// stage 16 rows x 256 cols f32 per wave (8 iters), then flush as 16 fully
// contiguous 1KB store instructions (one per row). No barriers: same wave
// writes and reads its LDS region (lgkmcnt ordering is compiler-inserted).
template <int ITERS>
__global__ __launch_bounds__(256) void gat_m(const unsigned* __restrict__ mask32,
        const short* __restrict__ htbP, const float* __restrict__ s1,
        const float* __restrict__ s2, const float* __restrict__ psum,
        float* __restrict__ att, float* __restrict__ hpp) {
    __shared__ float stg[4][16][260];          // 260 f32 row stride: 16B-aligned,
                                               // breaks 16-way write conflicts
    const int w = threadIdx.x >> 6, lane = threadIdx.x & 63;
    const int hh = w & 1, cs = w >> 1;
    const int pc = blockIdx.x * 2 + cs;        // col chunk
    const int n0 = blockIdx.y * 16;
    const int r = lane & 15, g = lane >> 4;
    const int node = n0 + r;
    const float s1v = s1[hh * NNODES + node];
    const float ps  = psum[hh * NNODES + node];
    const bool uni = !(ps > 0.f);
    const float inv = uni ? (1.0f / (float)NNODES) : (1.0f / ps);
    const float* s2h = s2 + hh * NNODES;
    const unsigned* mrow = mask32 + (size_t)node * MASKW + pc * ITERS;
    const short* bb = htbP + (size_t)(hh * 192 + pc * ITERS) * 2048 + (size_t)lane * 8;
    const int cbase = pc * ITERS * 32;
    float* atth = att + (size_t)hh * NNODES * NNODES;
    float (*myst)[260] = stg[w];

    f32x4 acc0 = {0.f,0.f,0.f,0.f}, acc1 = {0.f,0.f,0.f,0.f};
    f32x4 acc2 = {0.f,0.f,0.f,0.f}, acc3 = {0.f,0.f,0.f,0.f};

    for (int it = 0; it < ITERS; ++it) {
        const int kb = cbase + it * 32 + g * 8;
        const unsigned mb = (mrow[it] >> (g * 8)) & 0xffu;
        float4 sa = *(const float4*)(s2h + kb);
        float4 sb = *(const float4*)(s2h + kb + 4);
        float p0 = pcalc(s1v, sa.x, mb & 1u,   uni, inv);
        float p1 = pcalc(s1v, sa.y, mb & 2u,   uni, inv);
        float p2 = pcalc(s1v, sa.z, mb & 4u,   uni, inv);
        float p3 = pcalc(s1v, sa.w, mb & 8u,   uni, inv);
        float p4 = pcalc(s1v, sb.x, mb & 16u,  uni, inv);
        float p5 = pcalc(s1v, sb.y, mb & 32u,  uni, inv);
        float p6 = pcalc(s1v, sb.z, mb & 64u,  uni, inv);
        float p7 = pcalc(s1v, sb.w, mb & 128u, uni, inv);
        // stage normalized f32 p into wave-private LDS (exact values for att)
        float* sp = &myst[r][(it & 7) * 32 + g * 8];
        *(f32x4*)(sp)     = f32x4{p0, p1, p2, p3};
        *(f32x4*)(sp + 4) = f32x4{p4, p5, p6, p7};
        short8 af = { f2bf_hw(p0), f2bf_hw(p1), f2bf_hw(p2), f2bf_hw(p3),
                      f2bf_hw(p4), f2bf_hw(p5), f2bf_hw(p6), f2bf_hw(p7) };
        const short* bp = bb + (size_t)it * 2048;
        short8 b0 = *(const short8*)(bp);
        short8 b1 = *(const short8*)(bp + 512);
        short8 b2 = *(const short8*)(bp + 1024);
        short8 b3 = *(const short8*)(bp + 1536);
        acc0 = __builtin_amdgcn_mfma_f32_16x16x32_bf16(af, b0, acc0, 0, 0, 0);
        acc1 = __builtin_amdgcn_mfma_f32_16x16x32_bf16(af, b1, acc1, 0, 0, 0);
        acc2 = __builtin_amdgcn_mfma_f32_16x16x32_bf16(af, b2, acc2, 0, 0, 0);
        acc3 = __builtin_amdgcn_mfma_f32_16x16x32_bf16(af, b3, acc3, 0, 0, 0);
        if ((it & 7) == 7) {
            // flush 16 rows x 256 cols: one contiguous 1KB store inst per row
            const int colbase = cbase + (it - 7) * 32;
            #pragma unroll 4
            for (int rr = 0; rr < 16; ++rr) {
                f32x4 v = *(const f32x4*)&myst[rr][4 * lane];
                __builtin_nontemporal_store(v,
                    (f32x4*)(atth + (size_t)(n0 + rr) * NNODES + colbase + 4 * lane));
            }
        }
    }
    // A was normalized in-loop -> acc is final hp partial (R5 semantics)
    float* hb = hpp + ((size_t)(pc * NHEAD + hh) * NNODES + (n0 + g * 4)) * FOUTC + r;
    #pragma unroll
    for (int reg = 0; reg < 4; ++reg) {
        hb[(size_t)reg * FOUTC +  0] = acc0[reg];
        hb[(size_t)reg * FOUTC + 16] = acc1[reg];
        hb[(size_t)reg * FOUTC + 32] = acc2[reg];
        hb[(size_t)reg * FOUTC + 48] = acc3[reg];
    }
}

// K4: sum nchunk hp partials per head, layernorm over 128 features, write out
__global__ __launch_bounds__(256) void gat_k4(const float* __restrict__ hpp,
        const float* __restrict__ gamma, const float* __restrict__ beta,
        float* __restrict__ out, int nchunk) {
    const int wid = threadIdx.x >> 6, lane = threadIdx.x & 63;
    const int n = blockIdx.x * 4 + wid;
    float v0 = 0.f, v1 = 0.f;
    for (int p = 0; p < nchunk; ++p) {
        v0 += hpp[((size_t)(p * NHEAD + 0) * NNODES + n) * FOUTC + lane];
        v1 += hpp[((size_t)(p * NHEAD + 1) * NNODES + n) * FOUTC + lane];
    }
    float s = v0 + v1;
    #pragma unroll
    for (int off = 32; off; off >>= 1) s += __shfl_xor(s, off);
    const float mu = s * (1.0f / 128.0f);
    const float d0 = v0 - mu, d1 = v1 - mu;
    float q = d0 * d0 + d1 * d1;
    #pragma unroll
    for (int off = 32; off; off >>= 1) q += __shfl_xor(q, off);
    const float rstd = 1.0f / sqrtf(q * (1.0f / 128.0f) + LN_EPS);
    out[(size_t)n * 128 + lane]      = d0 * rstd * gamma[lane] + beta[lane];
    out[(size_t)n * 128 + 64 + lane] = d1 * rstd * gamma[64 + lane] + beta[64 + lane];
}

extern "C" void kernel_launch(void* const* d_in, const int* in_sizes, int n_in,
                              void* d_out, int out_size, void* d_ws, size_t ws_size,
                              hipStream_t stream) {
    const float* h     = (const float*)d_in[0];
    const int*   adj   = (const int*)d_in[1];
    const float* W     = (const float*)d_in[2];
    const float* a     = (const float*)d_in[3];
    const float* gamma = (const float*)d_in[4];
    const float* beta  = (const float*)d_in[5];
    float* out = (float*)d_out;
    float* att = out + (size_t)NNODES * (NHEAD * FOUTC);   // out first, then att

    char* ws = (char*)d_ws;
    short* htbP = (short*)ws;                               // 1,572,864 B
    float* s1   = (float*)(ws + 1572864);                   // 49,152 B
    float* s2p  = (float*)(ws + 1572864 + 49152);           // 49,152 B
    float* psum = (float*)(ws + 1572864 + 2 * 49152);       // 49,152 B
    unsigned* mask32 = (unsigned*)(ws + 1572864 + 3 * 49152);        // 4,718,592 B
    char* hpp_base = ws + 1572864 + 3 * 49152 + 4718592;             // = 6,438,912
    size_t avail = (ws_size > 6438912) ? ws_size - 6438912 : 0;
    const size_t per_chunk = (size_t)NHEAD * NNODES * FOUTC * 4;     // 3,145,728 B
    int nchunk = 2;
    if (avail >= 8 * per_chunk)      nchunk = 8;
    else if (avail >= 4 * per_chunk) nchunk = 4;
    float* hpp = (float*)hpp_base;

    gat_k1<<<NNODES / 4, 256, 0, stream>>>(h, W, a, htbP, s1, s2p);
    gat_k2a<<<NNODES, 256, 0, stream>>>(adj, s1, s2p, psum, mask32);
    dim3 gm(nchunk / 2, NNODES / 16);
    if (nchunk == 8)
        gat_m<24><<<gm, 256, 0, stream>>>(mask32, htbP, s1, s2p, psum, att, hpp);
    else if (nchunk == 4)
        gat_m<48><<<gm, 256, 0, stream>>>(mask32, htbP, s1, s2p, psum, att, hpp);
    else
        gat_m<96><<<gm, 256, 0, stream>>>(mask32, htbP, s1, s2p, psum, att, hpp);
    gat_k4<<<NNODES / 4, 256, 0, stream>>>(hpp, gamma, beta, out, nchunk);
}